// Round 1
// baseline (1603.672 us; speedup 1.0000x reference)
//
#include <hip/hip_runtime.h>
#include <stdint.h>

#define DEVINL __device__ __forceinline__

typedef __bf16 bf16x8 __attribute__((ext_vector_type(8)));
typedef float f32x4 __attribute__((ext_vector_type(4)));

DEVINL unsigned short f32_to_bf16(float f) {
  union { float f; uint32_t u; } v;
  v.f = f;
  uint32_t r = v.u + 0x7fffu + ((v.u >> 16) & 1u);  // RNE (inputs are finite)
  return (unsigned short)(r >> 16);
}

// async global->LDS, 16B per lane; LDS dest is wave-uniform base + lane*16
DEVINL void load16_to_lds(const void* g, void* l) {
  __builtin_amdgcn_global_load_lds(
      (const __attribute__((address_space(1))) void*)g,
      (__attribute__((address_space(3))) void*)l, 16, 0, 0);
}

// W [K][Nsrc] fp32 (row-major) -> Wt [Npad][K] bf16, zero-filled for n >= Nsrc.
// Grid: (K/32, Npad/32), block 256.
__global__ void transpose_cast_kernel(const float* __restrict__ W,
                                      unsigned short* __restrict__ Wt,
                                      int K, int Nsrc) {
  __shared__ float tile[32][33];
  const int k0 = blockIdx.x * 32;
  const int n0 = blockIdx.y * 32;
  const int t = threadIdx.x;
#pragma unroll
  for (int i = 0; i < 4; ++i) {
    int idx = t + 256 * i;
    int r = idx >> 5, c = idx & 31;  // r: k within tile, c: n within tile
    int gn = n0 + c;
    float v = (gn < Nsrc) ? W[(size_t)(k0 + r) * Nsrc + gn] : 0.0f;
    tile[r][c] = v;
  }
  __syncthreads();
#pragma unroll
  for (int i = 0; i < 4; ++i) {
    int idx = t + 256 * i;
    int n = idx >> 5, k = idx & 31;  // consecutive lanes -> consecutive k: coalesced
    Wt[(size_t)(n0 + n) * K + (k0 + k)] = f32_to_bf16(tile[k][n]);
  }
}

// C[m][n] = sum_k A[m][k] * Bt[n][k]  (+bias, then ReLU->bf16 or mask->fp32)
// A: fp32 (convert-on-stage) or bf16.  Bt: bf16 [Npad][K].
// Block: 256 threads = 4 waves in 2x2 grid; wave tile = (WM*16) x (WN*16).
template <int BM, int BN, bool A_F32, bool RELU_BF16_OUT>
__global__ __launch_bounds__(256) void gemm_kernel(
    const void* __restrict__ Ap, const unsigned short* __restrict__ Bt,
    const float* __restrict__ bias, unsigned short* __restrict__ Hout,
    float* __restrict__ Fout, const int* __restrict__ mask, int K, int Nout,
    int ldo) {
  constexpr int WM = BM / 32;
  constexpr int WN = BN / 32;
  __shared__ alignas(16) unsigned short Asmem[BM * 32];
  __shared__ alignas(16) unsigned short Bsmem[BN * 32];

  const int tid = threadIdx.x;
  const int wave = tid >> 6, lane = tid & 63;
  const int wm = wave >> 1, wn = wave & 1;
  const int m0 = blockIdx.y * BM;
  const int n0 = blockIdx.x * BN;

  const float* Af = (const float*)Ap;
  const unsigned short* Ab = (const unsigned short*)Ap;

  f32x4 acc[WM][WN] = {};

  for (int k0 = 0; k0 < K; k0 += 32) {
    if constexpr (A_F32) {
      // 128x32 fp32 tile: 256 threads x NF4 float4 loads, cvt to bf16, 8B LDS
      // writes at byte offset idx*8 -> contiguous, conflict-free.
      constexpr int NF4 = (BM * 32) / (256 * 4);
#pragma unroll
      for (int i = 0; i < NF4; ++i) {
        int idx = tid + 256 * i;
        int r = idx >> 3, c4 = idx & 7;
        float4 v = *reinterpret_cast<const float4*>(
            Af + (size_t)(m0 + r) * K + (k0 + c4 * 4));
        uint2 p;
        p.x = (uint32_t)f32_to_bf16(v.x) | ((uint32_t)f32_to_bf16(v.y) << 16);
        p.y = (uint32_t)f32_to_bf16(v.z) | ((uint32_t)f32_to_bf16(v.w) << 16);
        *reinterpret_cast<uint2*>(&Asmem[r * 32 + c4 * 4]) = p;
      }
    } else {
      // bf16 A: async 16B/lane direct-to-LDS; chunk c = 16 rows = 1024B.
      for (int c = wave; c < BM / 16; c += 4) {
        int row = c * 16 + (lane >> 2);
        load16_to_lds(Ab + (size_t)(m0 + row) * K + (k0 + (lane & 3) * 8),
                      &Asmem[c * 512]);
      }
    }
    for (int c = wave; c < BN / 16; c += 4) {
      int row = c * 16 + (lane >> 2);
      load16_to_lds(Bt + (size_t)(n0 + row) * K + (k0 + (lane & 3) * 8),
                    &Bsmem[c * 512]);
    }
    __syncthreads();

    // Fragments: A[m=lane&15][k=quad*8+j], B[n=lane&15][k=quad*8+j]
    // Both tiles stored [row][32k] bf16 -> ds_read_b128, conflict-free.
    bf16x8 a[WM], b[WN];
#pragma unroll
    for (int i = 0; i < WM; ++i)
      a[i] = *reinterpret_cast<const bf16x8*>(
          &Asmem[(wm * WM * 16 + i * 16 + (lane & 15)) * 32 + (lane >> 4) * 8]);
#pragma unroll
    for (int j = 0; j < WN; ++j)
      b[j] = *reinterpret_cast<const bf16x8*>(
          &Bsmem[(wn * WN * 16 + j * 16 + (lane & 15)) * 32 + (lane >> 4) * 8]);
#pragma unroll
    for (int i = 0; i < WM; ++i)
#pragma unroll
      for (int j = 0; j < WN; ++j)
        acc[i][j] = __builtin_amdgcn_mfma_f32_16x16x32_bf16(a[i], b[j],
                                                            acc[i][j], 0, 0, 0);
    __syncthreads();
  }

  // Epilogue. C/D layout: col(n) = lane&15, row(m) = (lane>>4)*4 + reg.
  const int l15 = lane & 15, quad = lane >> 4;
#pragma unroll
  for (int j = 0; j < WN; ++j) {
    int n = n0 + wn * WN * 16 + j * 16 + l15;
    if (n >= Nout) continue;  // only triggers in GEMM3 (Npad=96 > 81)
    float bn = bias[n];
#pragma unroll
    for (int i = 0; i < WM; ++i) {
      int mb = m0 + wm * WM * 16 + i * 16 + quad * 4;
      f32x4 v = acc[i][j];
#pragma unroll
      for (int r = 0; r < 4; ++r) {
        int m = mb + r;
        if constexpr (RELU_BF16_OUT) {
          Hout[(size_t)m * ldo + n] = f32_to_bf16(fmaxf(v[r] + bn, 0.0f));
        } else {
          Fout[(size_t)m * ldo + n] = (v[r] + bn) * (mask[m] ? 1.0f : 0.0f);
        }
      }
    }
  }
}

// Problem constants: B=16, N=512 -> M=8192 rows; FLAT=12544, HID=1024, NC=81.
extern "C" void kernel_launch(void* const* d_in, const int* in_sizes, int n_in,
                              void* d_out, int out_size, void* d_ws,
                              size_t ws_size, hipStream_t stream) {
  const float* feat = (const float*)d_in[0];  // [8192][12544] fp32
  const int* mask = (const int*)d_in[1];      // [8192] int (0/1)
  const float* W1 = (const float*)d_in[2];    // [12544][1024]
  const float* b1 = (const float*)d_in[3];
  const float* W2 = (const float*)d_in[4];    // [1024][1024]
  const float* b2 = (const float*)d_in[5];
  const float* W3 = (const float*)d_in[6];    // [1024][81]
  const float* b3 = (const float*)d_in[7];
  float* out = (float*)d_out;                 // [8192][81] fp32

  char* ws = (char*)d_ws;
  unsigned short* W1t = (unsigned short*)ws;  // [1024][12544] bf16, 25690112 B
  unsigned short* W2t = (unsigned short*)(ws + 25690112);  // [1024][1024]
  unsigned short* W3t = (unsigned short*)(ws + 25690112 + 2097152);  // [96][1024]
  unsigned short* H1 =
      (unsigned short*)(ws + 25690112 + 2097152 + 196608);  // [8192][1024]
  unsigned short* H2 =
      (unsigned short*)(ws + 25690112 + 2097152 + 196608 + 16777216);
  // total ws use: ~61.5 MB

  transpose_cast_kernel<<<dim3(392, 32), 256, 0, stream>>>(W1, W1t, 12544, 1024);
  transpose_cast_kernel<<<dim3(32, 32), 256, 0, stream>>>(W2, W2t, 1024, 1024);
  transpose_cast_kernel<<<dim3(32, 3), 256, 0, stream>>>(W3, W3t, 1024, 81);

  // GEMM1: h1 = relu(feat @ W1 + b1) -> bf16
  gemm_kernel<128, 128, true, true><<<dim3(8, 64), 256, 0, stream>>>(
      feat, W1t, b1, H1, nullptr, nullptr, 12544, 1024, 1024);
  // GEMM2: h2 = relu(h1 @ W2 + b2) -> bf16
  gemm_kernel<128, 128, false, true><<<dim3(8, 64), 256, 0, stream>>>(
      H1, W2t, b2, H2, nullptr, nullptr, 1024, 1024, 1024);
  // GEMM3: out = (h2 @ W3 + b3) * mask -> fp32
  gemm_kernel<64, 96, false, false><<<dim3(1, 128), 256, 0, stream>>>(
      H2, W3t, b3, nullptr, out, mask, 1024, 81, 81);
}

// Round 2
// 1041.115 us; speedup vs baseline: 1.5403x; 1.5403x over previous
//
#include <hip/hip_runtime.h>
#include <stdint.h>

#define DEVINL __device__ __forceinline__

typedef __bf16 bf16x8 __attribute__((ext_vector_type(8)));
typedef float f32x4 __attribute__((ext_vector_type(4)));

DEVINL unsigned short f32_to_bf16(float f) {
  union { float f; uint32_t u; } v;
  v.f = f;
  uint32_t r = v.u + 0x7fffu + ((v.u >> 16) & 1u);  // RNE (inputs are finite)
  return (unsigned short)(r >> 16);
}

// async global->LDS, 16B per lane; LDS dest is wave-uniform base + lane*16
DEVINL void load16_to_lds(const void* g, void* l) {
  __builtin_amdgcn_global_load_lds(
      (const __attribute__((address_space(1))) void*)g,
      (__attribute__((address_space(3))) void*)l, 16, 0, 0);
}

// fp32 -> bf16 bulk cast. Each thread: 8 elems (2x float4 in, 1x uint4 out).
__global__ __launch_bounds__(256) void cast_f32_bf16_kernel(
    const float* __restrict__ in, unsigned short* __restrict__ out) {
  size_t idx = (size_t)blockIdx.x * 256 + threadIdx.x;
  const float4* in4 = (const float4*)in;
  float4 a = in4[2 * idx];
  float4 b = in4[2 * idx + 1];
  uint4 p;
  p.x = (uint32_t)f32_to_bf16(a.x) | ((uint32_t)f32_to_bf16(a.y) << 16);
  p.y = (uint32_t)f32_to_bf16(a.z) | ((uint32_t)f32_to_bf16(a.w) << 16);
  p.z = (uint32_t)f32_to_bf16(b.x) | ((uint32_t)f32_to_bf16(b.y) << 16);
  p.w = (uint32_t)f32_to_bf16(b.z) | ((uint32_t)f32_to_bf16(b.w) << 16);
  reinterpret_cast<uint4*>(out)[idx] = p;
}

// W [K][Nsrc] fp32 (row-major) -> Wt [Npad][K] bf16, zero-filled for n >= Nsrc.
// Grid: (K/32, Npad/32), block 256.
__global__ void transpose_cast_kernel(const float* __restrict__ W,
                                      unsigned short* __restrict__ Wt,
                                      int K, int Nsrc) {
  __shared__ float tile[32][33];
  const int k0 = blockIdx.x * 32;
  const int n0 = blockIdx.y * 32;
  const int t = threadIdx.x;
#pragma unroll
  for (int i = 0; i < 4; ++i) {
    int idx = t + 256 * i;
    int r = idx >> 5, c = idx & 31;
    int gn = n0 + c;
    float v = (gn < Nsrc) ? W[(size_t)(k0 + r) * Nsrc + gn] : 0.0f;
    tile[r][c] = v;
  }
  __syncthreads();
#pragma unroll
  for (int i = 0; i < 4; ++i) {
    int idx = t + 256 * i;
    int n = idx >> 5, k = idx & 31;
    Wt[(size_t)(n0 + n) * K + (k0 + k)] = f32_to_bf16(tile[k][n]);
  }
}

// C[m][n] = sum_k A[m][k] * Bt[n][k]  (+bias, then ReLU->bf16 or mask->fp32)
// A: fp32 (convert-on-stage, fallback only) or bf16 (async global_load_lds).
// Block: 256 threads = 4 waves in 2x2 grid; wave tile = (WM*16) x (WN*16).
template <int BM, int BN, bool A_F32, bool RELU_BF16_OUT>
__global__ __launch_bounds__(256) void gemm_kernel(
    const void* __restrict__ Ap, const unsigned short* __restrict__ Bt,
    const float* __restrict__ bias, unsigned short* __restrict__ Hout,
    float* __restrict__ Fout, const int* __restrict__ mask, int K, int Nout,
    int ldo) {
  constexpr int WM = BM / 32;
  constexpr int WN = BN / 32;
  __shared__ alignas(16) unsigned short Asmem[BM * 32];
  __shared__ alignas(16) unsigned short Bsmem[BN * 32];

  const int tid = threadIdx.x;
  const int wave = tid >> 6, lane = tid & 63;
  const int wm = wave >> 1, wn = wave & 1;
  const int m0 = blockIdx.y * BM;
  const int n0 = blockIdx.x * BN;

  const float* Af = (const float*)Ap;
  const unsigned short* Ab = (const unsigned short*)Ap;

  f32x4 acc[WM][WN] = {};

  for (int k0 = 0; k0 < K; k0 += 32) {
    if constexpr (A_F32) {
      constexpr int NF4 = (BM * 32) / (256 * 4);
#pragma unroll
      for (int i = 0; i < NF4; ++i) {
        int idx = tid + 256 * i;
        int r = idx >> 3, c4 = idx & 7;
        float4 v = *reinterpret_cast<const float4*>(
            Af + (size_t)(m0 + r) * K + (k0 + c4 * 4));
        uint2 p;
        p.x = (uint32_t)f32_to_bf16(v.x) | ((uint32_t)f32_to_bf16(v.y) << 16);
        p.y = (uint32_t)f32_to_bf16(v.z) | ((uint32_t)f32_to_bf16(v.w) << 16);
        *reinterpret_cast<uint2*>(&Asmem[r * 32 + c4 * 4]) = p;
      }
    } else {
      // async 16B/lane direct-to-LDS; chunk c = 16 rows = 1024B contiguous.
#pragma unroll
      for (int c = wave; c < BM / 16; c += 4) {
        int row = c * 16 + (lane >> 2);
        load16_to_lds(Ab + (size_t)(m0 + row) * K + (k0 + (lane & 3) * 8),
                      &Asmem[c * 512]);
      }
    }
#pragma unroll
    for (int c = wave; c < BN / 16; c += 4) {
      int row = c * 16 + (lane >> 2);
      load16_to_lds(Bt + (size_t)(n0 + row) * K + (k0 + (lane & 3) * 8),
                    &Bsmem[c * 512]);
    }
    __syncthreads();

    // Fragments: A[m=lane&15][k=quad*8+j], B[n=lane&15][k=quad*8+j]
    bf16x8 a[WM], b[WN];
#pragma unroll
    for (int i = 0; i < WM; ++i)
      a[i] = *reinterpret_cast<const bf16x8*>(
          &Asmem[(wm * WM * 16 + i * 16 + (lane & 15)) * 32 + (lane >> 4) * 8]);
#pragma unroll
    for (int j = 0; j < WN; ++j)
      b[j] = *reinterpret_cast<const bf16x8*>(
          &Bsmem[(wn * WN * 16 + j * 16 + (lane & 15)) * 32 + (lane >> 4) * 8]);
#pragma unroll
    for (int i = 0; i < WM; ++i)
#pragma unroll
      for (int j = 0; j < WN; ++j)
        acc[i][j] = __builtin_amdgcn_mfma_f32_16x16x32_bf16(a[i], b[j],
                                                            acc[i][j], 0, 0, 0);
    __syncthreads();
  }

  // Epilogue. C/D layout: col(n) = lane&15, row(m) = (lane>>4)*4 + reg.
  const int l15 = lane & 15, quad = lane >> 4;
#pragma unroll
  for (int j = 0; j < WN; ++j) {
    int n = n0 + wn * WN * 16 + j * 16 + l15;
    if (n >= Nout) continue;  // only triggers in GEMM3 (Npad=96 > 81)
    float bn = bias[n];
#pragma unroll
    for (int i = 0; i < WM; ++i) {
      int mb = m0 + wm * WM * 16 + i * 16 + quad * 4;
      f32x4 v = acc[i][j];
#pragma unroll
      for (int r = 0; r < 4; ++r) {
        int m = mb + r;
        if constexpr (RELU_BF16_OUT) {
          Hout[(size_t)m * ldo + n] = f32_to_bf16(fmaxf(v[r] + bn, 0.0f));
        } else {
          Fout[(size_t)m * ldo + n] = (v[r] + bn) * (mask[m] ? 1.0f : 0.0f);
        }
      }
    }
  }
}

// Problem constants: B=16, N=512 -> M=8192 rows; FLAT=12544, HID=1024, NC=81.
extern "C" void kernel_launch(void* const* d_in, const int* in_sizes, int n_in,
                              void* d_out, int out_size, void* d_ws,
                              size_t ws_size, hipStream_t stream) {
  const float* feat = (const float*)d_in[0];  // [8192][12544] fp32
  const int* mask = (const int*)d_in[1];      // [8192] int (0/1)
  const float* W1 = (const float*)d_in[2];    // [12544][1024]
  const float* b1 = (const float*)d_in[3];
  const float* W2 = (const float*)d_in[4];    // [1024][1024]
  const float* b2 = (const float*)d_in[5];
  const float* W3 = (const float*)d_in[6];    // [1024][81]
  const float* b3 = (const float*)d_in[7];
  float* out = (float*)d_out;                 // [8192][81] fp32

  char* ws = (char*)d_ws;
  size_t off = 0;
  unsigned short* W1t = (unsigned short*)(ws + off); off += 25690112;  // [1024][12544]
  unsigned short* W2t = (unsigned short*)(ws + off); off += 2097152;   // [1024][1024]
  unsigned short* W3t = (unsigned short*)(ws + off); off += 196608;    // [96][1024]
  unsigned short* H1  = (unsigned short*)(ws + off); off += 16777216;  // [8192][1024]
  unsigned short* H2  = (unsigned short*)(ws + off); off += 16777216;  // [8192][1024]
  unsigned short* Fb  = (unsigned short*)(ws + off);                   // [8192][12544]
  size_t need = off + 205520896;

  transpose_cast_kernel<<<dim3(392, 32), 256, 0, stream>>>(W1, W1t, 12544, 1024);
  transpose_cast_kernel<<<dim3(32, 32), 256, 0, stream>>>(W2, W2t, 1024, 1024);
  transpose_cast_kernel<<<dim3(32, 3), 256, 0, stream>>>(W3, W3t, 1024, 81);

  if (ws_size >= need) {
    // Pre-cast features to bf16 (411 MB -> 206 MB), then all-async GEMM1.
    cast_f32_bf16_kernel<<<50176, 256, 0, stream>>>(feat, Fb);
    gemm_kernel<64, 128, false, true><<<dim3(8, 128), 256, 0, stream>>>(
        Fb, W1t, b1, H1, nullptr, nullptr, 12544, 1024, 1024);
  } else {
    // Fallback: fused convert-on-stage (slower but no big buffer).
    gemm_kernel<128, 128, true, true><<<dim3(8, 64), 256, 0, stream>>>(
        feat, W1t, b1, H1, nullptr, nullptr, 12544, 1024, 1024);
  }
  // GEMM2: h2 = relu(h1 @ W2 + b2) -> bf16
  gemm_kernel<64, 128, false, true><<<dim3(8, 128), 256, 0, stream>>>(
      H1, W2t, b2, H2, nullptr, nullptr, 1024, 1024, 1024);
  // GEMM3: out = (h2 @ W3 + b3) * mask -> fp32
  gemm_kernel<64, 96, false, false><<<dim3(1, 128), 256, 0, stream>>>(
      H2, W3t, b3, nullptr, out, mask, 1024, 81, 81);
}

// Round 3
// 1003.600 us; speedup vs baseline: 1.5979x; 1.0374x over previous
//
#include <hip/hip_runtime.h>
#include <stdint.h>

#define DEVINL __device__ __forceinline__

typedef __bf16 bf16x8 __attribute__((ext_vector_type(8)));
typedef float f32x4 __attribute__((ext_vector_type(4)));

DEVINL unsigned short f32_to_bf16(float f) {
  union { float f; uint32_t u; } v;
  v.f = f;
  uint32_t r = v.u + 0x7fffu + ((v.u >> 16) & 1u);  // RNE (inputs are finite)
  return (unsigned short)(r >> 16);
}

// async global->LDS, 16B per lane; LDS dest is wave-uniform base + lane*16
DEVINL void load16_to_lds(const void* g, void* l) {
  __builtin_amdgcn_global_load_lds(
      (const __attribute__((address_space(1))) void*)g,
      (__attribute__((address_space(3))) void*)l, 16, 0, 0);
}

// fp32 -> bf16 bulk cast. Each thread: 8 elems (2x float4 in, 1x uint4 out).
__global__ __launch_bounds__(256) void cast_f32_bf16_kernel(
    const float* __restrict__ in, unsigned short* __restrict__ out) {
  size_t idx = (size_t)blockIdx.x * 256 + threadIdx.x;
  const float4* in4 = (const float4*)in;
  float4 a = in4[2 * idx];
  float4 b = in4[2 * idx + 1];
  uint4 p;
  p.x = (uint32_t)f32_to_bf16(a.x) | ((uint32_t)f32_to_bf16(a.y) << 16);
  p.y = (uint32_t)f32_to_bf16(a.z) | ((uint32_t)f32_to_bf16(a.w) << 16);
  p.z = (uint32_t)f32_to_bf16(b.x) | ((uint32_t)f32_to_bf16(b.y) << 16);
  p.w = (uint32_t)f32_to_bf16(b.z) | ((uint32_t)f32_to_bf16(b.w) << 16);
  reinterpret_cast<uint4*>(out)[idx] = p;
}

// W [K][Nsrc] fp32 (row-major) -> Wt [Npad][K] bf16, zero-filled for n >= Nsrc.
// Grid: (K/32, Npad/32), block 256.
__global__ void transpose_cast_kernel(const float* __restrict__ W,
                                      unsigned short* __restrict__ Wt,
                                      int K, int Nsrc) {
  __shared__ float tile[32][33];
  const int k0 = blockIdx.x * 32;
  const int n0 = blockIdx.y * 32;
  const int t = threadIdx.x;
#pragma unroll
  for (int i = 0; i < 4; ++i) {
    int idx = t + 256 * i;
    int r = idx >> 5, c = idx & 31;
    int gn = n0 + c;
    float v = (gn < Nsrc) ? W[(size_t)(k0 + r) * Nsrc + gn] : 0.0f;
    tile[r][c] = v;
  }
  __syncthreads();
#pragma unroll
  for (int i = 0; i < 4; ++i) {
    int idx = t + 256 * i;
    int n = idx >> 5, k = idx & 31;
    Wt[(size_t)(n0 + n) * K + (k0 + k)] = f32_to_bf16(tile[k][n]);
  }
}

// C[m][n] = sum_k A[m][k] * Bt[n][k]  (+bias, then ReLU->bf16 or mask->fp32)
// A: fp32 (convert-on-stage, fallback only) or bf16 (async global_load_lds).
// Block: 256 threads = 4 waves in 2x2 grid; wave tile = (WM*16) x (WN*16).
// Primary config BM=BN=128: WM=WN=4 -> 16 MFMA : 8 ds_read_b128 per wave-iter
// (m97 histogram; 64-tile halves MFMA amortization and cost R2 ~1.6x on GEMM1).
template <int BM, int BN, bool A_F32, bool RELU_BF16_OUT>
__global__ __launch_bounds__(256) void gemm_kernel(
    const void* __restrict__ Ap, const unsigned short* __restrict__ Bt,
    const float* __restrict__ bias, unsigned short* __restrict__ Hout,
    float* __restrict__ Fout, const int* __restrict__ mask, int K, int Nout,
    int ldo) {
  constexpr int WM = BM / 32;
  constexpr int WN = BN / 32;
  __shared__ alignas(16) unsigned short Asmem[BM * 32];
  __shared__ alignas(16) unsigned short Bsmem[BN * 32];

  const int tid = threadIdx.x;
  const int wave = tid >> 6, lane = tid & 63;
  const int wm = wave >> 1, wn = wave & 1;
  const int m0 = blockIdx.y * BM;
  const int n0 = blockIdx.x * BN;

  const float* Af = (const float*)Ap;
  const unsigned short* Ab = (const unsigned short*)Ap;

  f32x4 acc[WM][WN] = {};

  for (int k0 = 0; k0 < K; k0 += 32) {
    if constexpr (A_F32) {
      constexpr int NF4 = (BM * 32) / (256 * 4);
#pragma unroll
      for (int i = 0; i < NF4; ++i) {
        int idx = tid + 256 * i;
        int r = idx >> 3, c4 = idx & 7;
        float4 v = *reinterpret_cast<const float4*>(
            Af + (size_t)(m0 + r) * K + (k0 + c4 * 4));
        uint2 p;
        p.x = (uint32_t)f32_to_bf16(v.x) | ((uint32_t)f32_to_bf16(v.y) << 16);
        p.y = (uint32_t)f32_to_bf16(v.z) | ((uint32_t)f32_to_bf16(v.w) << 16);
        *reinterpret_cast<uint2*>(&Asmem[r * 32 + c4 * 4]) = p;
      }
    } else {
      // async 16B/lane direct-to-LDS; chunk c = 16 rows = 1024B contiguous.
#pragma unroll
      for (int c = wave; c < BM / 16; c += 4) {
        int row = c * 16 + (lane >> 2);
        load16_to_lds(Ab + (size_t)(m0 + row) * K + (k0 + (lane & 3) * 8),
                      &Asmem[c * 512]);
      }
    }
#pragma unroll
    for (int c = wave; c < BN / 16; c += 4) {
      int row = c * 16 + (lane >> 2);
      load16_to_lds(Bt + (size_t)(n0 + row) * K + (k0 + (lane & 3) * 8),
                    &Bsmem[c * 512]);
    }
    __syncthreads();

    // Fragments: A[m=lane&15][k=quad*8+j], B[n=lane&15][k=quad*8+j]
    bf16x8 a[WM], b[WN];
#pragma unroll
    for (int i = 0; i < WM; ++i)
      a[i] = *reinterpret_cast<const bf16x8*>(
          &Asmem[(wm * WM * 16 + i * 16 + (lane & 15)) * 32 + (lane >> 4) * 8]);
#pragma unroll
    for (int j = 0; j < WN; ++j)
      b[j] = *reinterpret_cast<const bf16x8*>(
          &Bsmem[(wn * WN * 16 + j * 16 + (lane & 15)) * 32 + (lane >> 4) * 8]);
#pragma unroll
    for (int i = 0; i < WM; ++i)
#pragma unroll
      for (int j = 0; j < WN; ++j)
        acc[i][j] = __builtin_amdgcn_mfma_f32_16x16x32_bf16(a[i], b[j],
                                                            acc[i][j], 0, 0, 0);
    __syncthreads();
  }

  // Epilogue. C/D layout: col(n) = lane&15, row(m) = (lane>>4)*4 + reg.
  const int l15 = lane & 15, quad = lane >> 4;
#pragma unroll
  for (int j = 0; j < WN; ++j) {
    int n = n0 + wn * WN * 16 + j * 16 + l15;
    if (n >= Nout) continue;  // only triggers in GEMM3 (Npad=96 > 81)
    float bn = bias[n];
#pragma unroll
    for (int i = 0; i < WM; ++i) {
      int mb = m0 + wm * WM * 16 + i * 16 + quad * 4;
      f32x4 v = acc[i][j];
#pragma unroll
      for (int r = 0; r < 4; ++r) {
        int m = mb + r;
        if constexpr (RELU_BF16_OUT) {
          Hout[(size_t)m * ldo + n] = f32_to_bf16(fmaxf(v[r] + bn, 0.0f));
        } else {
          Fout[(size_t)m * ldo + n] = (v[r] + bn) * (mask[m] ? 1.0f : 0.0f);
        }
      }
    }
  }
}

// Problem constants: B=16, N=512 -> M=8192 rows; FLAT=12544, HID=1024, NC=81.
extern "C" void kernel_launch(void* const* d_in, const int* in_sizes, int n_in,
                              void* d_out, int out_size, void* d_ws,
                              size_t ws_size, hipStream_t stream) {
  const float* feat = (const float*)d_in[0];  // [8192][12544] fp32
  const int* mask = (const int*)d_in[1];      // [8192] int (0/1)
  const float* W1 = (const float*)d_in[2];    // [12544][1024]
  const float* b1 = (const float*)d_in[3];
  const float* W2 = (const float*)d_in[4];    // [1024][1024]
  const float* b2 = (const float*)d_in[5];
  const float* W3 = (const float*)d_in[6];    // [1024][81]
  const float* b3 = (const float*)d_in[7];
  float* out = (float*)d_out;                 // [8192][81] fp32

  char* ws = (char*)d_ws;
  size_t off = 0;
  unsigned short* W1t = (unsigned short*)(ws + off); off += 25690112;  // [1024][12544]
  unsigned short* W2t = (unsigned short*)(ws + off); off += 2097152;   // [1024][1024]
  unsigned short* W3t = (unsigned short*)(ws + off); off += 196608;    // [96][1024]
  unsigned short* H1  = (unsigned short*)(ws + off); off += 16777216;  // [8192][1024]
  unsigned short* H2  = (unsigned short*)(ws + off); off += 16777216;  // [8192][1024]
  unsigned short* Fb  = (unsigned short*)(ws + off);                   // [8192][12544]
  size_t need = off + 205520896;

  transpose_cast_kernel<<<dim3(392, 32), 256, 0, stream>>>(W1, W1t, 12544, 1024);
  transpose_cast_kernel<<<dim3(32, 32), 256, 0, stream>>>(W2, W2t, 1024, 1024);
  transpose_cast_kernel<<<dim3(32, 3), 256, 0, stream>>>(W3, W3t, 1024, 81);

  if (ws_size >= need) {
    // Pre-cast features to bf16 (411 MB -> 206 MB), then all-async GEMM1.
    cast_f32_bf16_kernel<<<50176, 256, 0, stream>>>(feat, Fb);
    gemm_kernel<128, 128, false, true><<<dim3(8, 64), 256, 0, stream>>>(
        Fb, W1t, b1, H1, nullptr, nullptr, 12544, 1024, 1024);
  } else {
    // Fallback: fused convert-on-stage (slower but no big buffer).
    gemm_kernel<128, 128, true, true><<<dim3(8, 64), 256, 0, stream>>>(
        feat, W1t, b1, H1, nullptr, nullptr, 12544, 1024, 1024);
  }
  // GEMM2: h2 = relu(h1 @ W2 + b2) -> bf16
  gemm_kernel<128, 128, false, true><<<dim3(8, 64), 256, 0, stream>>>(
      H1, W2t, b2, H2, nullptr, nullptr, 1024, 1024, 1024);
  // GEMM3: out = (h2 @ W3 + b3) * mask -> fp32  (BM=32 -> 256 blocks, 1/CU)
  gemm_kernel<32, 96, false, false><<<dim3(1, 256), 256, 0, stream>>>(
      H2, W3t, b3, nullptr, out, mask, 1024, 81, 81);
}